// Round 9
// baseline (216.032 us; speedup 1.0000x reference)
//
#include <hip/hip_runtime.h>

// Y = (Bm@A) @ a_term + (Bm@C) @ c_term as one bf16 MFMA GEMM.
// R13: true streaming via LDS-address double-buffering. Seven kernels (R4-R12)
// pinned at 67-71 us with every pipe <25% busy: the limiter is SUSTAINED
// outstanding loads (~7 KB/CU vs ~22 KB/CU needed for peak BW), and every
// VGPR-based prefetch attempt was de-pipelined by the compiler (R11 spilled,
// R12 coalesced the double buffer). Fix: global_load_lds async DMA (no dest
// VGPRs, buffers distinguished by LDS address - nothing to coalesce) with
// hand-counted vmcnt waits (m97/m201 pattern):
//   iter t: issue stage(t+1) -> s_waitcnt vmcnt(12) [stage(t) done; stage(t+1)
//   9 DMAs + 3 stores stay in flight] -> extract -> geometry -> MFMA -> store
//   -> lgkmcnt(0) fence (D-region ds_reads complete before next DMA clobber).
// Each wave: 8 tiles x 4 points, 9 KB continuously outstanding; 8 waves/CU
// = 72 KB/CU sustained (3x full-BW requirement). afrag in 64 VGPRs (once per
// wave, L2-hot; R4 proved affordable). NO __syncthreads (all LDS wave-private).
// LDS: 4 waves x 2 bufs x 2304 dwords = 73,728 B -> 2 blocks/CU (256,2).
// Buffer layout (dwords): [0..1535] J tile (4x384) / Z rows / D epilogue,
// [1536..2303] X tile (4x192). Z row (pi,i) at pi*204 + i*68.

typedef __bf16 bf16x8 __attribute__((ext_vector_type(8)));
typedef float floatx4 __attribute__((ext_vector_type(4)));

#define ZRS 68  // Z row stride in dwords (136 bf16: K=128 + 8 pad)

__global__ __launch_bounds__(64) void prep_kernel(const float* __restrict__ A,
                                                  const float* __restrict__ Bm,
                                                  const float* __restrict__ C,
                                                  __bf16* __restrict__ acat) {
    int tid = blockIdx.x * 64 + threadIdx.x;  // 0..4095, one wave per block
    int f = tid >> 6;
    int e = tid & 63;
    float m = 0.f, m2 = 0.f;
    #pragma unroll 8
    for (int k = 0; k < 64; ++k) {
        float b = Bm[f * 64 + k];
        m  = fmaf(b, A[k * 64 + e], m);
        m2 = fmaf(b, C[k * 64 + e], m2);
    }
    // logical (f, k): k=2e -> (Bm@A)[f,e], k=2e+1 -> (Bm@C)[f,e]; stored in
    // MFMA fragment order p(f,k) = ((mt*4+kc)*64 + quad*16 + l15)*8 + (k&7).
    int mt  = f >> 4, l15 = f & 15;
    int k1  = 2 * e;
    int kc  = k1 >> 5;
    int qd  = (k1 >> 3) & 3;
    int j   = k1 & 7;  // even, so j+1 stays in the same 8-elem group
    int p   = ((mt * 4 + kc) * 64 + qd * 16 + l15) * 8 + j;
    acat[p]     = (__bf16)m;
    acat[p + 1] = (__bf16)m2;
}

static __device__ __forceinline__ unsigned pk(float a, float c) {
    unsigned short ua = __builtin_bit_cast(unsigned short, (__bf16)a);
    unsigned short uc = __builtin_bit_cast(unsigned short, (__bf16)c);
    return ((unsigned)uc << 16) | ua;
}

// async DMA: 16 B per lane, LDS dest = uniform base + lane*16 (linear).
static __device__ __forceinline__ void glds16(const float* g, float* l) {
    __builtin_amdgcn_global_load_lds(
        (const __attribute__((address_space(1))) void*)g,
        (__attribute__((address_space(3))) void*)l, 16, 0, 0);
}

__global__ __launch_bounds__(256, 2) void main_kernel(const float* __restrict__ X,
                                                      const float* __restrict__ J,
                                                      const __bf16* __restrict__ acat,
                                                      float* __restrict__ out) {
    __shared__ __align__(16) float lds[4 * 2 * 2304];  // 73,728 B -> 2 blocks/CU

    const int tid  = threadIdx.x;
    const int wave = tid >> 6;
    const int lane = tid & 63;
    const int l15  = lane & 15;
    const int quad = lane >> 4;
    const size_t pw0 = ((size_t)blockIdx.x * 4 + wave) * 32;  // 32 points/wave

    float* buf0 = lds + wave * 4608;
    float* buf1 = buf0 + 2304;

    // ---- afrag: 64 VGPRs, loaded once per wave (L2-hot, fragment order) ----
    bf16x8 afrag[4][4];
    #pragma unroll
    for (int mt = 0; mt < 4; ++mt)
        #pragma unroll
        for (int kc = 0; kc < 4; ++kc)
            afrag[mt][kc] = *(const bf16x8*)(acat + ((mt * 4 + kc) * 64 + lane) * 8);

    // ---- stage one 4-point tile into an LDS buffer: 9 async DMAs ----
    auto stage = [&](int tile, float* dst) {
        const float* jg = J + (pw0 + tile * 4) * 384 + lane * 4;
        const float* xg = X + (pw0 + tile * 4) * 192 + lane * 4;
        #pragma unroll
        for (int u = 0; u < 6; ++u) glds16(jg + u * 256, dst + u * 256);
        #pragma unroll
        for (int u = 0; u < 3; ++u) glds16(xg + u * 256, dst + 1536 + u * 256);
    };

    stage(0, buf0);

    #pragma unroll 2
    for (int t = 0; t < 8; ++t) {
        float* cur = (t & 1) ? buf1 : buf0;
        float* nxt = (t & 1) ? buf0 : buf1;

        // ---- issue next tile's DMAs first (in flight through whole iter) ----
        if (t < 7) stage(t + 1, nxt);

        // ---- wait for stage(t) ONLY (oldest-first vmcnt semantics):
        // t=0: queue = afrag(16)+stage0(9)+stage1(9) -> drain to 9.
        // 1<=t<7: queue = stage(t)(9)+stores(t-1)(3)+stage(t+1)(9) -> drain to 12.
        // t=7: queue = stage7(9)+stores6(3) -> drain to 3.
        if (t == 0)      asm volatile("s_waitcnt vmcnt(9)" ::: "memory");
        else if (t == 7) asm volatile("s_waitcnt vmcnt(3)" ::: "memory");
        else             asm volatile("s_waitcnt vmcnt(12)" ::: "memory");

        // ---- extract J/X to registers (frees J region for Z) ----
        float2 jr[4][3];
        float  xr[4][3];
        #pragma unroll
        for (int pi = 0; pi < 4; ++pi) {
            const float* jst = cur + pi * 384 + lane * 6;   // lane = d
            jr[pi][0] = *(const float2*)(jst);
            jr[pi][1] = *(const float2*)(jst + 2);
            jr[pi][2] = *(const float2*)(jst + 4);
            const float* xst = cur + 1536 + pi * 192 + lane * 3;
            xr[pi][0] = xst[0]; xr[pi][1] = xst[1]; xr[pi][2] = xst[2];
        }

        // ---- geometry: lane = d; Z rows into cur's (consumed) J region ----
        #pragma unroll
        for (int pi = 0; pi < 4; ++pi) {
            float a0x = jr[pi][0].x, a1x = jr[pi][0].y;  // record [i][j] row-major
            float a0y = jr[pi][1].x, a1y = jr[pi][1].y;
            float a0z = jr[pi][2].x, a1z = jr[pi][2].y;
            float xx = xr[pi][0], xy = xr[pi][1], xz = xr[pi][2];

            float n0 = sqrtf(a0x * a0x + a0y * a0y + a0z * a0z);
            float r0 = 1.0f / fmaxf(n0, 1e-12f);
            float b1x = a0x * r0, b1y = a0y * r0, b1z = a0z * r0;

            float d  = b1x * a1x + b1y * a1y + b1z * a1z;
            float ux = a1x - d * b1x, uy = a1y - d * b1y, uz = a1z - d * b1z;
            float n2 = sqrtf(ux * ux + uy * uy + uz * uz);
            float r2 = 1.0f / fmaxf(n2, 1e-12f);
            float b2x = ux * r2, b2y = uy * r2, b2z = uz * r2;

            float b3x = b1y * b2z - b1z * b2y;
            float b3y = b1z * b2x - b1x * b2z;
            float b3z = b1x * b2y - b1y * b2x;

            float rt0 = b1x * xx + b1y * xy + b1z * xz;
            float rt1 = b2x * xx + b2y * xy + b2z * xz;
            float rt2 = b3x * xx + b3y * xy + b3z * xz;

            float s = rt1 - rt2, tt = rt1 + rt2;

            unsigned* zr = (unsigned*)cur + pi * (3 * ZRS);  // rows (pi, 0..2)
            zr[lane]           = pk(b2x * s + b3x * tt, b1x * rt0);
            zr[ZRS + lane]     = pk(b2y * s + b3y * tt, b1y * rt0);
            zr[2 * ZRS + lane] = pk(b2z * s + b3z * tt, b1z * rt0);
        }

        // ---- MFMA: 16x mfma 16x16x32, K=128, rows 0..11 valid ----
        floatx4 acc[4];
        #pragma unroll
        for (int mt = 0; mt < 4; ++mt) acc[mt] = (floatx4){0.f, 0.f, 0.f, 0.f};

        int row = l15 > 11 ? 11 : l15;  // clamp: n>=12 columns garbage, never stored
        int pz  = (row * 21846) >> 16;  // row / 3
        int iz  = row - pz * 3;
        const __bf16* zb = (const __bf16*)cur + pz * (3 * ZRS * 2) + iz * (ZRS * 2);
        #pragma unroll
        for (int kc = 0; kc < 4; ++kc) {
            bf16x8 b = *(const bf16x8*)(zb + kc * 32 + quad * 8);
            #pragma unroll
            for (int mt = 0; mt < 4; ++mt)
                acc[mt] = __builtin_amdgcn_mfma_f32_16x16x32_bf16(afrag[mt][kc], b, acc[mt], 0, 0, 0);
        }

        // ---- epilogue: D[f][n] -> cur [p_local*196 + f*3 + i] (aliases Z) ----
        float* dl = cur;
        #pragma unroll
        for (int mt = 0; mt < 4; ++mt) {
            int n = l15;
            if (n < 12) {
                int pl = (n * 21846) >> 16;  // n / 3
                int i  = n - pl * 3;
                float* dst = dl + pl * 196 + i;
                #pragma unroll
                for (int r = 0; r < 4; ++r) {
                    int f = mt * 16 + quad * 4 + r;
                    dst[f * 3] = acc[mt][r];
                }
            }
        }

        // ---- coalesced store: 4 points x 48 float4 (same-wave DS in-order) ----
        floatx4* og = (floatx4*)(out + (pw0 + t * 4) * 192);
        #pragma unroll
        for (int u = 0; u < 3; ++u) {
            int g  = u * 64 + lane;
            int pg = (g * 1366) >> 16;  // g / 48
            int o  = g - pg * 48;
            og[g] = *(const floatx4*)(dl + pg * 196 + o * 4);
        }

        // ---- fence: D-region ds_reads retired before next iter's DMA can
        //      clobber cur (memory clobber also pins DMA issue below). ----
        asm volatile("s_waitcnt lgkmcnt(0)" ::: "memory");
    }
}

extern "C" void kernel_launch(void* const* d_in, const int* in_sizes, int n_in,
                              void* d_out, int out_size, void* d_ws, size_t ws_size,
                              hipStream_t stream) {
    const float* X  = (const float*)d_in[0];
    const float* J  = (const float*)d_in[1];
    const float* A  = (const float*)d_in[2];
    const float* Bm = (const float*)d_in[3];
    const float* C  = (const float*)d_in[4];
    float* out = (float*)d_out;
    __bf16* acat = (__bf16*)d_ws;  // 64x128 bf16 = 16 KB, fragment order

    prep_kernel<<<64, 64, 0, stream>>>(A, Bm, C, acat);

    // 65536 points = 512 blocks x 4 waves x 8 tiles x 4 points (exact fit,
    // 2 blocks/CU -> whole grid resident at once, zero turnover)
    main_kernel<<<512, 256, 0, stream>>>(X, J, acat, out);
}